// Round 1
// baseline (270.731 us; speedup 1.0000x reference)
//
#include <hip/hip_runtime.h>
#include <stdint.h>

// 64x64 bf16 planes in LDS, unpadded stride 64, XOR-swizzled:
//   element [r][c] at short-index r*64 + (((c>>3) ^ (r&7))<<3) + (c&7)
//   R-plane: row-major; T-plane: transposed.
// NEW SCHEME (vs previous 16x16 version):
//   * mfma_f32_32x32x16: each wave owns one 32x32 quadrant (wr,wc).
//   * mirror product mfma(b,a) -> C^T acc -> via permlane32_swap assembled
//     into 2 contiguous short8 row-fragments: used BOTH as 2x ds_write_b128
//     (R-plane) AND as next round's A-fragment own-k-half (register forward).
//   * primary product mfma(a,b) -> same assembly -> T-plane stores + next
//     round's B-fragment own-half. Only rounds m3,m6,m15,m30 need primaries.
//   * Per round each wave reads only the NEIGHBOR halves (2-4 ds_read_b128),
//     paired with register halves by global k-index (wave-uniform wr==wc rule).
#define PL 4096  // shorts per plane

typedef unsigned int u32;
typedef unsigned short u16;
typedef float f32x4 __attribute__((ext_vector_type(4)));
typedef float f32x16 __attribute__((ext_vector_type(16)));
typedef short short8 __attribute__((ext_vector_type(8)));
typedef unsigned int u32x2 __attribute__((ext_vector_type(2)));

__device__ __forceinline__ u32 prm(u32 a, u32 b, u32 s) {
  return __builtin_amdgcn_perm(a, b, s);
}
__device__ __forceinline__ u32 pk(float f0, float f1) {  // {bf16 f0, bf16 f1}
  return prm(__float_as_uint(f1), __float_as_uint(f0), 0x07060302u);
}
__device__ __forceinline__ float rlo(u32 w) { return __uint_as_float(w << 16); }
__device__ __forceinline__ float rhi(u32 w) {
  return __uint_as_float(w & 0xffff0000u);
}

__device__ __forceinline__ short8 mk8(u32 w0, u32 w1, u32 w2, u32 w3) {
  union {
    u32 w[4];
    short8 s;
  } u;
  u.w[0] = w0;
  u.w[1] = w1;
  u.w[2] = w2;
  u.w[3] = w3;
  return u.s;
}

__device__ __forceinline__ f32x16 MF(short8 a, short8 b, f32x16 c) {
  return __builtin_amdgcn_mfma_f32_32x32x16_bf16(a, b, c, 0, 0, 0);
}

__device__ __forceinline__ f32x16 Z16() {
  f32x16 z;
#pragma unroll
  for (int i = 0; i < 16; ++i) z[i] = 0.0f;
  return z;
}

// 32x32 C/D acc: reg r holds offset (r&3) + 8*(r>>2) + 4*h (h = lane>>5) at
// index lane&31 of the other dim. Assemble two contiguous 8-elem bf16 frags:
// F_fl covers offsets 16*fl + 8*h + {0..7}. permlane32_swap(ux,vx) yields
// word0 (out[0]) and word2 (out[1]) for BOTH halves (HK T12 wiring).
__device__ __forceinline__ void frags(const f32x16& a, short8& F0, short8& F1) {
  {
    u32 ux = pk(a[0], a[1]), uy = pk(a[2], a[3]);
    u32 vx = pk(a[4], a[5]), vy = pk(a[6], a[7]);
    u32x2 s0 = __builtin_amdgcn_permlane32_swap(ux, vx, false, false);
    u32x2 s1 = __builtin_amdgcn_permlane32_swap(uy, vy, false, false);
    F0 = mk8(s0[0], s1[0], s0[1], s1[1]);
  }
  {
    u32 ux = pk(a[8], a[9]), uy = pk(a[10], a[11]);
    u32 vx = pk(a[12], a[13]), vy = pk(a[14], a[15]);
    u32x2 s0 = __builtin_amdgcn_permlane32_swap(ux, vx, false, false);
    u32x2 s1 = __builtin_amdgcn_permlane32_swap(uy, vy, false, false);
    F1 = mk8(s0[0], s1[0], s0[1], s1[1]);
  }
}

__device__ __forceinline__ void dot8(short8 a, short8 b, float& part) {
  union {
    short8 s;
    u32 w[4];
  } ua, ub;
  ua.s = a;
  ub.s = b;
#pragma unroll
  for (int w = 0; w < 4; ++w) {
    part = fmaf(rlo(ua.w[w]), rlo(ub.w[w]), part);
    part = fmaf(rhi(ua.w[w]), rhi(ub.w[w]), part);
  }
}

// Plane slot schedule (static, 1-periodic):
//   stage: W S0=R(m), S1=T(m)
//   c1  m2 : R S0,S1(cF)      -> W S2=R2           (mirror only)
//   c2  m3 : R S2             -> W S3=R3, S4=T3    (dual; pb -> cC own)
//   c3  m6 : R S4(cC-oth),S3  -> W S0=R6, S1=T6    (dual; pb -> c4 bf own)
//   c4  m12: R S0,S1          -> W S2=R12          (mirror only)
//   c5  m15: R S2             -> W S3=R15, S0=T15  (dual; pb -> f1 bf own)
//   f1  m30: R S3,S0          -> W S1=R30, S2=T30  (dual + free trace)
//   f2  m60: R S1,S2          -> W S4=R60          (mirror only)
//   f3  m63: R S4             -> W S5=R63          (mirror only)
//   gradprox: R S5 (pcol patches)
__global__ __launch_bounds__(256, 2) void dag_iter_kernel(
    const float* __restrict__ adj, float* __restrict__ out) {
  __shared__ __align__(16) u16 BUF[6 * PL];
  __shared__ float red[2];
  u16* S0 = BUF;
  u16* S1 = BUF + PL;
  u16* S2 = BUF + 2 * PL;
  u16* S3 = BUF + 3 * PL;
  u16* S4 = BUF + 4 * PL;
  u16* S5 = BUF + 5 * PL;

  // De-phase the two co-resident blocks on a CU.
  if ((blockIdx.x >> 8) & 1) __builtin_amdgcn_s_sleep(6);

  const int tid = (int)threadIdx.x;
  const int lane = tid & 63;
  const int wv = tid >> 6;
  const int wr = wv >> 1;  // row quadrant
  const int wc = wv & 1;   // col quadrant
  const int l31 = lane & 31;
  const int h = lane >> 5;
  const bool diag = (wr == wc);
  const bool wcz = (wc == 0);

  const int rA = 32 * wr + l31;  // R-plane row for af reads / mirror stores
  const int rB = 32 * wc + l31;  // T-plane row for bf reads / primary stores
  const int mA = rA & 7, mB = rB & 7;

  int rdAF[4], rdBF[4];  // full-matrix frag reads (c1 only)
#pragma unroll
  for (int f = 0; f < 4; ++f) {
    rdAF[f] = rA * 64 + (((2 * f + h) ^ mA) << 3);
    rdBF[f] = rB * 64 + (((2 * f + h) ^ mB) << 3);
  }
  const int foA = (1 - wc) << 2;  // cg base of af neighbor half
  const int foB = (1 - wr) << 2;  // cg base of bf neighbor half
  const int rdA0 = rA * 64 + (((foA + 0 + h) ^ mA) << 3);
  const int rdA1 = rA * 64 + (((foA + 2 + h) ^ mA) << 3);
  const int rdB0 = rB * 64 + (((foB + 0 + h) ^ mB) << 3);
  const int rdB1 = rB * 64 + (((foB + 2 + h) ^ mB) << 3);
  const int stR0 = rA * 64 + ((((wc << 2) + 0 + h) ^ mA) << 3);
  const int stR1 = rA * 64 + ((((wc << 2) + 2 + h) ^ mA) << 3);
  const int stT0 = rB * 64 + ((((wr << 2) + 0 + h) ^ mB) << 3);
  const int stT1 = rB * 64 + ((((wr << 2) + 2 + h) ^ mB) << 3);

  // 4x4 elementwise patch per thread.
  const int r0 = (tid & 15) << 2;
  const int c0 = (tid >> 4) << 2;
  int prow[4], pcol[4];
#pragma unroll
  for (int i = 0; i < 4; ++i) {
    prow[i] =
        (r0 + i) * 64 + ((((c0 >> 3) ^ ((r0 + i) & 7))) << 3) + (c0 & 7);
    pcol[i] =
        (c0 + i) * 64 + ((((r0 >> 3) ^ ((c0 + i) & 7))) << 3) + (r0 & 7);
  }

  const float* src = adj + (size_t)blockIdx.x * 4096;
  float x[4][4], sc[4][4];
#pragma unroll
  for (int i = 0; i < 4; ++i) {
    f32x4 v = *(const f32x4*)(src + (r0 + i) * 64 + c0);
#pragma unroll
    for (int j = 0; j < 4; ++j) {
      x[i][j] = v[j];
      sc[i][j] = (v[j] > 0.5f) ? v[j] : 0.0f;
    }
  }
  float alpha = 0.0f;

  // Persistent register fragments.
  short8 nxA0 = {}, nxA1 = {};  // next-round af own-half (from mirror)
  short8 pb0 = {}, pb1 = {};    // next-round bf own-half (from primary)
  short8 cF0 = {}, cF1 = {}, cF2 = {}, cF3 = {};  // bf of m (c1,c2)
  short8 cCo0 = {}, cCo1 = {}, cCl0 = {}, cCl1 = {};  // bf of m3 (c3,c5,f3)

  auto prox = [&](float til[4][4]) {
#pragma unroll
    for (int i = 0; i < 4; ++i)
#pragma unroll
      for (int j = 0; j < 4; ++j) {
        float ax = fabsf(til[i][j]) - 2e-5f;
        float nx = ax > 0.0f ? ax : 0.0f;
        x[i][j] = nx > 1.0f ? 1.0f : nx;
      }
  };

  auto stage = [&]() {  // m = I + x.*x/64 -> S0 (R), S1 (T)
    float m[4][4];
#pragma unroll
    for (int i = 0; i < 4; ++i)
#pragma unroll
      for (int j = 0; j < 4; ++j)
        m[i][j] = fmaf(x[i][j] * x[i][j], 0.015625f,
                       (r0 + i == c0 + j) ? 1.0f : 0.0f);
#pragma unroll
    for (int i = 0; i < 4; ++i)
      *(uint2*)(S0 + prow[i]) =
          make_uint2(pk(m[i][0], m[i][1]), pk(m[i][2], m[i][3]));
#pragma unroll
    for (int j = 0; j < 4; ++j)
      *(uint2*)(S1 + pcol[j]) =
          make_uint2(pk(m[0][j], m[1][j]), pk(m[2][j], m[3][j]));
    __syncthreads();
  };

  auto gradprox = [&]() {  // alpha from red; m63^T patches from R63 (S5)
    float tr = red[0] + red[1];
    alpha = fmaf(0.01f, tr * 0.015625f - 1.0f, alpha);
    const float a2 = alpha * 0.03125f;  // 2*alpha/64
    float til[4][4];
#pragma unroll
    for (int j = 0; j < 4; ++j) {
      uint2 w = *(const uint2*)(S5 + pcol[j]);
      float pt[4] = {rlo(w.x), rhi(w.x), rlo(w.y), rhi(w.y)};
#pragma unroll
      for (int i = 0; i < 4; ++i) {
        float g = fmaf(a2 * x[i][j], pt[i], -sc[i][j]);
        til[i][j] = fmaf(-0.01f, g, x[i][j]);
      }
    }
    prox(til);
  };

  auto c1 = [&]() {  // m2 = m@m : mirror only -> S2 + forward af
    short8 a0 = *(const short8*)(S0 + rdAF[0]);
    short8 a1 = *(const short8*)(S0 + rdAF[1]);
    short8 a2 = *(const short8*)(S0 + rdAF[2]);
    short8 a3 = *(const short8*)(S0 + rdAF[3]);
    cF0 = *(const short8*)(S1 + rdBF[0]);
    cF1 = *(const short8*)(S1 + rdBF[1]);
    cF2 = *(const short8*)(S1 + rdBF[2]);
    cF3 = *(const short8*)(S1 + rdBF[3]);
    f32x16 m = Z16();
    m = MF(cF0, a0, m);
    m = MF(cF1, a1, m);
    m = MF(cF2, a2, m);
    m = MF(cF3, a3, m);
    frags(m, nxA0, nxA1);
    *(short8*)(S2 + stR0) = nxA0;
    *(short8*)(S2 + stR1) = nxA1;
    __syncthreads();
  };

  auto c2 = [&]() {  // m3 = m2@m : dual -> S3(R3), S4(T3); pb = bf3 own
    short8 aL0 = *(const short8*)(S2 + rdA0);
    short8 aL1 = *(const short8*)(S2 + rdA1);
    f32x16 m = Z16(), p = Z16();
    if (wcz) {
      m = MF(cF0, nxA0, m);
      m = MF(cF1, nxA1, m);
      m = MF(cF2, aL0, m);
      m = MF(cF3, aL1, m);
      p = MF(nxA0, cF0, p);
      p = MF(nxA1, cF1, p);
      p = MF(aL0, cF2, p);
      p = MF(aL1, cF3, p);
    } else {
      m = MF(cF2, nxA0, m);
      m = MF(cF3, nxA1, m);
      m = MF(cF0, aL0, m);
      m = MF(cF1, aL1, m);
      p = MF(nxA0, cF2, p);
      p = MF(nxA1, cF3, p);
      p = MF(aL0, cF0, p);
      p = MF(aL1, cF1, p);
    }
    frags(m, nxA0, nxA1);
    frags(p, pb0, pb1);
    *(short8*)(S3 + stR0) = nxA0;
    *(short8*)(S3 + stR1) = nxA1;
    *(short8*)(S4 + stT0) = pb0;
    *(short8*)(S4 + stT1) = pb1;
    __syncthreads();
  };

  auto c3 = [&]() {  // m6 = m3@m3 : dual -> S0(R6), S1(T6); cC = bf of m3
    cCl0 = *(const short8*)(S4 + rdB0);
    cCl1 = *(const short8*)(S4 + rdB1);
    cCo0 = pb0;
    cCo1 = pb1;
    short8 aL0 = *(const short8*)(S3 + rdA0);
    short8 aL1 = *(const short8*)(S3 + rdA1);
    f32x16 m = Z16(), p = Z16();
    if (diag) {
      m = MF(cCo0, nxA0, m);
      m = MF(cCo1, nxA1, m);
      m = MF(cCl0, aL0, m);
      m = MF(cCl1, aL1, m);
      p = MF(nxA0, cCo0, p);
      p = MF(nxA1, cCo1, p);
      p = MF(aL0, cCl0, p);
      p = MF(aL1, cCl1, p);
    } else {
      m = MF(cCl0, nxA0, m);
      m = MF(cCl1, nxA1, m);
      m = MF(cCo0, aL0, m);
      m = MF(cCo1, aL1, m);
      p = MF(nxA0, cCl0, p);
      p = MF(nxA1, cCl1, p);
      p = MF(aL0, cCo0, p);
      p = MF(aL1, cCo1, p);
    }
    frags(m, nxA0, nxA1);
    frags(p, pb0, pb1);
    *(short8*)(S0 + stR0) = nxA0;
    *(short8*)(S0 + stR1) = nxA1;
    *(short8*)(S1 + stT0) = pb0;
    *(short8*)(S1 + stT1) = pb1;
    __syncthreads();
  };

  auto c4 = [&]() {  // m12 = m6@m6 : mirror only -> S2(R12)
    short8 aL0 = *(const short8*)(S0 + rdA0);
    short8 aL1 = *(const short8*)(S0 + rdA1);
    short8 bL0 = *(const short8*)(S1 + rdB0);
    short8 bL1 = *(const short8*)(S1 + rdB1);
    f32x16 m = Z16();
    if (diag) {
      m = MF(pb0, nxA0, m);
      m = MF(pb1, nxA1, m);
      m = MF(bL0, aL0, m);
      m = MF(bL1, aL1, m);
    } else {
      m = MF(bL0, nxA0, m);
      m = MF(bL1, nxA1, m);
      m = MF(pb0, aL0, m);
      m = MF(pb1, aL1, m);
    }
    frags(m, nxA0, nxA1);
    *(short8*)(S2 + stR0) = nxA0;
    *(short8*)(S2 + stR1) = nxA1;
    __syncthreads();
  };

  auto c5 = [&]() {  // m15 = m12@m3 : dual -> S3(R15), S0(T15)
    short8 aL0 = *(const short8*)(S2 + rdA0);
    short8 aL1 = *(const short8*)(S2 + rdA1);
    f32x16 m = Z16(), p = Z16();
    if (diag) {
      m = MF(cCo0, nxA0, m);
      m = MF(cCo1, nxA1, m);
      m = MF(cCl0, aL0, m);
      m = MF(cCl1, aL1, m);
      p = MF(nxA0, cCo0, p);
      p = MF(nxA1, cCo1, p);
      p = MF(aL0, cCl0, p);
      p = MF(aL1, cCl1, p);
    } else {
      m = MF(cCl0, nxA0, m);
      m = MF(cCl1, nxA1, m);
      m = MF(cCo0, aL0, m);
      m = MF(cCo1, aL1, m);
      p = MF(nxA0, cCl0, p);
      p = MF(nxA1, cCl1, p);
      p = MF(aL0, cCo0, p);
      p = MF(aL1, cCo1, p);
    }
    frags(m, nxA0, nxA1);
    frags(p, pb0, pb1);
    *(short8*)(S3 + stR0) = nxA0;
    *(short8*)(S3 + stR1) = nxA1;
    *(short8*)(S0 + stT0) = pb0;
    *(short8*)(S0 + stT1) = pb1;
    __syncthreads();
  };

  auto f1 = [&]() {  // m30 = m15@m15 : dual -> S1(R30), S2(T30) + free trace
    short8 aL0 = *(const short8*)(S3 + rdA0);
    short8 aL1 = *(const short8*)(S3 + rdA1);
    short8 bL0 = *(const short8*)(S0 + rdB0);
    short8 bL1 = *(const short8*)(S0 + rdB1);
    if (diag) {  // tr(m30) = sum m15 .* m15^T over aligned fragment pairs
      float part = 0.0f;
      dot8(nxA0, pb0, part);
      dot8(nxA1, pb1, part);
      dot8(aL0, bL0, part);
      dot8(aL1, bL1, part);
#pragma unroll
      for (int off = 1; off < 64; off <<= 1) part += __shfl_xor(part, off);
      if (lane == 0) red[wv == 0 ? 0 : 1] = part;
    }
    f32x16 m = Z16(), p = Z16();
    if (diag) {
      m = MF(pb0, nxA0, m);
      m = MF(pb1, nxA1, m);
      m = MF(bL0, aL0, m);
      m = MF(bL1, aL1, m);
      p = MF(nxA0, pb0, p);
      p = MF(nxA1, pb1, p);
      p = MF(aL0, bL0, p);
      p = MF(aL1, bL1, p);
    } else {
      m = MF(bL0, nxA0, m);
      m = MF(bL1, nxA1, m);
      m = MF(pb0, aL0, m);
      m = MF(pb1, aL1, m);
      p = MF(nxA0, bL0, p);
      p = MF(nxA1, bL1, p);
      p = MF(aL0, pb0, p);
      p = MF(aL1, pb1, p);
    }
    frags(m, nxA0, nxA1);
    frags(p, pb0, pb1);
    *(short8*)(S1 + stR0) = nxA0;
    *(short8*)(S1 + stR1) = nxA1;
    *(short8*)(S2 + stT0) = pb0;
    *(short8*)(S2 + stT1) = pb1;
    __syncthreads();
  };

  auto f2 = [&]() {  // m60 = m30@m30 : mirror only -> S4(R60)
    short8 aL0 = *(const short8*)(S1 + rdA0);
    short8 aL1 = *(const short8*)(S1 + rdA1);
    short8 bL0 = *(const short8*)(S2 + rdB0);
    short8 bL1 = *(const short8*)(S2 + rdB1);
    f32x16 m = Z16();
    if (diag) {
      m = MF(pb0, nxA0, m);
      m = MF(pb1, nxA1, m);
      m = MF(bL0, aL0, m);
      m = MF(bL1, aL1, m);
    } else {
      m = MF(bL0, nxA0, m);
      m = MF(bL1, nxA1, m);
      m = MF(pb0, aL0, m);
      m = MF(pb1, aL1, m);
    }
    frags(m, nxA0, nxA1);
    *(short8*)(S4 + stR0) = nxA0;
    *(short8*)(S4 + stR1) = nxA1;
    __syncthreads();
  };

  auto f3 = [&]() {  // m63 = m60@m3 : mirror only -> S5(R63)
    short8 aL0 = *(const short8*)(S4 + rdA0);
    short8 aL1 = *(const short8*)(S4 + rdA1);
    f32x16 m = Z16();
    if (diag) {
      m = MF(cCo0, nxA0, m);
      m = MF(cCo1, nxA1, m);
      m = MF(cCl0, aL0, m);
      m = MF(cCl1, aL1, m);
    } else {
      m = MF(cCl0, nxA0, m);
      m = MF(cCl1, nxA1, m);
      m = MF(cCo0, aL0, m);
      m = MF(cCo1, aL1, m);
    }
    frags(m, nxA0, nxA1);
    *(short8*)(S5 + stR0) = nxA0;
    *(short8*)(S5 + stR1) = nxA1;
    __syncthreads();
  };

  // ---- iteration 0: alpha == 0 -> grad = -scores ----
  {
    float til[4][4];
#pragma unroll
    for (int i = 0; i < 4; ++i)
#pragma unroll
      for (int j = 0; j < 4; ++j) til[i][j] = fmaf(0.01f, sc[i][j], x[i][j]);
    prox(til);
  }
  stage();
  c1();
  c2();
  c3();
  c4();
  c5();
  // ---- iterations 1..48 ----
  for (int it = 0; it < 48; ++it) {
    f1();
    f2();
    f3();
    gradprox();
    stage();
    c1();
    c2();
    c3();
    c4();
    c5();
  }
  // ---- iteration 49: no trailing stage/chain ----
  f1();
  f2();
  f3();
  gradprox();

  float* dst = out + (size_t)blockIdx.x * 4096;
#pragma unroll
  for (int i = 0; i < 4; ++i) {
    f32x4 v;
#pragma unroll
    for (int j = 0; j < 4; ++j) v[j] = (x[i][j] > 0.5f) ? x[i][j] : 0.0f;
    *(f32x4*)(dst + (r0 + i) * 64 + c0) = v;
  }
}

extern "C" void kernel_launch(void* const* d_in, const int* in_sizes, int n_in,
                              void* d_out, int out_size, void* d_ws,
                              size_t ws_size, hipStream_t stream) {
  const float* adj = (const float*)d_in[0];
  float* out = (float*)d_out;
  const int nbatch = in_sizes[0] / 4096;  // 512
  dag_iter_kernel<<<nbatch, 256, 0, stream>>>(adj, out);
}

// Round 2
// 265.203 us; speedup vs baseline: 1.0208x; 1.0208x over previous
//
#include <hip/hip_runtime.h>
#include <stdint.h>

// Each 64x64 matrix: bf16 planes in LDS, unpadded stride 64, XOR-swizzled:
//   element [r][c] at short-index  r*64 + (((c>>3) ^ (r&7))<<3) + (c&7)
//   R-plane: row-major (MFMA A-fragment = one b128)
//   T-plane: transposed (MFMA B-fragment = one b128)
// 6 fixed plane slots, 1-periodic schedule; all LDS addrs loop-invariant.
//
// ROUND-2 CHANGE vs round-0: 8 waves (512 thr) per matrix instead of 4.
// Wave w owns tile-row wr = w>>1 and tile-cols {2*(w&1), 2*(w&1)+1}:
// 2 output tiles per direction (was 4). Same schedule, same numerics.
// Rationale: grid (512 blocks) caps blocks/CU at 2, so occupancy was
// grid-capped at 21%; doubling threads/block doubles waves/SIMD (2->4)
// for latency hiding on this round-latency-bound kernel.
#define PL 4096  // shorts per plane

typedef unsigned int u32;
typedef unsigned short u16;
typedef float f32x4 __attribute__((ext_vector_type(4)));
typedef short short8 __attribute__((ext_vector_type(8)));

__device__ __forceinline__ u32 prm(u32 a, u32 b, u32 s) {
  return __builtin_amdgcn_perm(a, b, s);
}
__device__ __forceinline__ u32 pk(float f0, float f1) {  // {bf16 f0, bf16 f1}
  return prm(__float_as_uint(f1), __float_as_uint(f0), 0x07060302u);
}
__device__ __forceinline__ float rlo(u32 w) { return __uint_as_float(w << 16); }
__device__ __forceinline__ float rhi(u32 w) {
  return __uint_as_float(w & 0xffff0000u);
}

// Per-thread invariant LDS short-offsets (8-wave split: 1 tile-row band,
// 2 tile-cols per wave).
struct O {
  int ra[2];     // A-frag read [q] (k-half)
  int rb[2][2];  // B-frag read [tj][q]
  int sT[2];     // T-plane store for primary product tile tj
  int sR[2];     // R-plane store for mirror product tile tj
};

// B-fragment register cache: 4 b128 loads of one round's B-operand,
// reusable by any later round whose B-plane content is unchanged.
struct BF {
  short8 b0[2], b1[2];  // [tj] x k-half
};

__device__ __forceinline__ BF loadB(const u16* __restrict__ BT, const O& o) {
  BF f;
#pragma unroll
  for (int t = 0; t < 2; ++t) {
    f.b0[t] = *(const short8*)(BT + o.rb[t][0]);
    f.b1[t] = *(const short8*)(BT + o.rb[t][1]);
  }
  return f;
}

__device__ __forceinline__ void dot8(short8 a, short8 b, float& part) {
  union {
    short8 s;
    u32 w[4];
  } ua, ub;
  ua.s = a;
  ub.s = b;
#pragma unroll
  for (int w = 0; w < 4; ++w) {
    part = fmaf(rlo(ua.w[w]), rlo(ub.w[w]), part);
    part = fmaf(rhi(ua.w[w]), rhi(ub.w[w]), part);
  }
}

// C = A @ B (64x64 bf16). 8 waves; wave w owns 2 16x16 tiles per direction.
// Primary (a x b) -> C^T-contiguous -> T-plane; mirror (b x a) -> R-plane.
// WR/WT gate dead planes. TR: waves {0,2,5,7} have A-frags element-aligned
// with B-frag tile tj=(wv>>1)&1 (their tile-row == that tile-col), so
// sum R.*T over those 4 waves' fragments = tr(A*B) free when A=R15,B=T15.
// B-fragments come from a register cache. Dest planes != source planes.
// Trailing barrier.
template <bool WR, bool WT, bool TR = false>
__device__ __forceinline__ void mm_core(const u16* __restrict__ AR,
                                        const BF& bf, u16* __restrict__ CR,
                                        u16* __restrict__ CT, const O& o,
                                        float* red = nullptr) {
  short8 a0 = *(const short8*)(AR + o.ra[0]);
  short8 a1 = *(const short8*)(AR + o.ra[1]);
  if (TR) {
    const int tid = (int)threadIdx.x;
    const int wvv = tid >> 6;
    if ((wvv & 1) == ((wvv >> 2) & 1)) {  // trace waves 0,2,5,7
      const int tjt = (wvv >> 1) & 1;     // wave-uniform; select, not index
      short8 bt0 = tjt ? bf.b0[1] : bf.b0[0];
      short8 bt1 = tjt ? bf.b1[1] : bf.b1[0];
      float part = 0.0f;
      dot8(a0, bt0, part);
      dot8(a1, bt1, part);
#pragma unroll
      for (int off = 1; off < 64; off <<= 1) part += __shfl_xor(part, off);
      if ((tid & 63) == 0) red[wvv >> 1] = part;
    }
  }
  const f32x4 Z = {0.0f, 0.0f, 0.0f, 0.0f};
#pragma unroll
  for (int tj = 0; tj < 2; ++tj) {
    if (WT) {
      f32x4 acc =
          __builtin_amdgcn_mfma_f32_16x16x32_bf16(a0, bf.b0[tj], Z, 0, 0, 0);
      acc =
          __builtin_amdgcn_mfma_f32_16x16x32_bf16(a1, bf.b1[tj], acc, 0, 0, 0);
      *(uint2*)(CT + o.sT[tj]) =
          make_uint2(pk(acc[0], acc[1]), pk(acc[2], acc[3]));
    }
    if (WR) {
      f32x4 acc =
          __builtin_amdgcn_mfma_f32_16x16x32_bf16(bf.b0[tj], a0, Z, 0, 0, 0);
      acc =
          __builtin_amdgcn_mfma_f32_16x16x32_bf16(bf.b1[tj], a1, acc, 0, 0, 0);
      *(uint2*)(CR + o.sR[tj]) =
          make_uint2(pk(acc[0], acc[1]), pk(acc[2], acc[3]));
    }
  }
  __syncthreads();
}

template <bool WR, bool WT, bool TR = false>
__device__ __forceinline__ void mm(const u16* __restrict__ AR,
                                   const u16* __restrict__ BT,
                                   u16* __restrict__ CR, u16* __restrict__ CT,
                                   const O& o, float* red = nullptr) {
  BF bf = loadB(BT, o);
  mm_core<WR, WT, TR>(AR, bf, CR, CT, o, red);
}

// One block (512 thr = 8 waves) per batch element; 2 blocks/CU (grid-capped).
// Thread owns a 4x2 patch (r0=(tid&15)*4, c0=(tid>>4)*2) for elementwise work.
//
// 1-periodic 6-slot schedule, invariant entering each iter:
//   PA=R15, PB=T15, PC=T3  (of current x)
//   f1 m30:(PA,PB)->(PD,PE) [+free trace into red]   f2 m60:(PD,PE)->PF [R]
//   f3 m63:(PF,cC=T3)->PD [T]
//   g: gradprox (alpha from red, T63 from PD); stage m(new x)->(PE=R, PF=T)
//   c1 m2:(PE,PF->cF)->PD [R]  c2 m3:(PD,cF)->(PE=R3, PC=T3)
//   c3 m6:(PE,PC->cC)->(PD,PF) c4 m12:(PD,PF)->PE [R]
//   c5 m15:(PE,cC)->(PA,PB)
// cC (T3) stays in registers from c3 through next iter's f3; cF lives c1->c2.
__global__ __launch_bounds__(512, 4) void dag_iter_kernel(
    const float* __restrict__ adj, float* __restrict__ out) {
  __shared__ __align__(16) u16 BUF[6 * PL];
  __shared__ float red[4];
  u16* PA = BUF;
  u16* PB = BUF + PL;
  u16* PC = BUF + 2 * PL;
  u16* PD = BUF + 3 * PL;
  u16* PE = BUF + 4 * PL;
  u16* PF = BUF + 5 * PL;

  // De-phase the two co-resident blocks on a CU.
  if ((blockIdx.x >> 8) & 1) __builtin_amdgcn_s_sleep(11);

  const int tid = (int)threadIdx.x;
  const int lane = tid & 63;
  const int wv = tid >> 6;
  const int wr = wv >> 1;        // tile-row band 0..3
  const int wc2 = wv & 1;        // tile-col pair 0..1
  const int l15 = lane & 15;
  const int grp = lane >> 4;
  const int l7 = l15 & 7;
  const int r0 = (tid & 15) << 2;
  const int c0 = (tid >> 4) << 1;

  O o;
#pragma unroll
  for (int q = 0; q < 2; ++q) {
    const int koff = (((q << 2) + grp) ^ l7) << 3;
    o.ra[q] = (wr * 16 + l15) * 64 + koff;
#pragma unroll
    for (int t = 0; t < 2; ++t)
      o.rb[t][q] = ((2 * wc2 + t) * 16 + l15) * 64 + koff;
  }
#pragma unroll
  for (int tj = 0; tj < 2; ++tj) {
    const int a = wr;
    const int b = 2 * wc2 + tj;
    o.sT[tj] = (16 * b + l15) * 64 + (((2 * a + (grp >> 1)) ^ l7) << 3) +
               ((grp & 1) << 2);
    o.sR[tj] = (16 * a + l15) * 64 + (((2 * b + (grp >> 1)) ^ l7) << 3) +
               ((grp & 1) << 2);
  }
  int prow[4], pcol[2];
#pragma unroll
  for (int i = 0; i < 4; ++i)
    prow[i] =
        (r0 + i) * 64 + ((((c0 >> 3) ^ ((r0 + i) & 7))) << 3) + (c0 & 7);
#pragma unroll
  for (int j = 0; j < 2; ++j)
    pcol[j] =
        (c0 + j) * 64 + ((((r0 >> 3) ^ ((c0 + j) & 7))) << 3) + (r0 & 7);

  const float* src = adj + (size_t)blockIdx.x * 4096;
  float x[4][2], sc[4][2];
#pragma unroll
  for (int i = 0; i < 4; ++i) {
    float2 v = *(const float2*)(src + (r0 + i) * 64 + c0);
    x[i][0] = v.x;
    x[i][1] = v.y;
    sc[i][0] = (v.x > 0.5f) ? v.x : 0.0f;
    sc[i][1] = (v.y > 0.5f) ? v.y : 0.0f;
  }
  float alpha = 0.0f;
  BF cC;  // register cache of T3's B-fragments (c3 -> c5 -> next f3)

  auto prox = [&](float til[4][2]) {
#pragma unroll
    for (int i = 0; i < 4; ++i)
#pragma unroll
      for (int j = 0; j < 2; ++j) {
        float ax = fabsf(til[i][j]) - 2e-5f;
        float nx = ax > 0.0f ? ax : 0.0f;
        x[i][j] = nx > 1.0f ? 1.0f : nx;
      }
  };
  auto stage = [&]() {  // m = I + x.*x/64 -> PE (R-plane), PF (T-plane)
    float m[4][2];
#pragma unroll
    for (int i = 0; i < 4; ++i)
#pragma unroll
      for (int j = 0; j < 2; ++j)
        m[i][j] = fmaf(x[i][j] * x[i][j], 0.015625f,
                       (r0 + i == c0 + j) ? 1.0f : 0.0f);
#pragma unroll
    for (int i = 0; i < 4; ++i)
      *(u32*)(PE + prow[i]) = pk(m[i][0], m[i][1]);
#pragma unroll
    for (int j = 0; j < 2; ++j)
      *(uint2*)(PF + pcol[j]) =
          make_uint2(pk(m[0][j], m[1][j]), pk(m[2][j], m[3][j]));
    __syncthreads();
  };
  auto chain5 = [&]() {  // sources: PE=R(m), PF=T(m)
    BF cF = loadB(PF, o);                     // T(m), reused by c2
    mm_core<true, false>(PE, cF, PD, PD, o);  // c1: m2 -> R only
    mm_core<true, true>(PD, cF, PE, PC, o);   // c2: m3 -> (R3, T3)
    cC = loadB(PC, o);                        // T3, reused by c5 and next f3
    mm_core<true, true>(PE, cC, PD, PF, o);   // c3: m6 = m3^2
    mm<true, false>(PD, PF, PE, PE, o);       // c4: m12 -> R only
    mm_core<true, true>(PE, cC, PA, PB, o);   // c5: m15 -> (PA,PB)
  };
  auto gradprox = [&]() {  // alpha from red (tr(m30) of x_i); T63 in PD
    float tr = red[0] + red[1] + red[2] + red[3];
    alpha = fmaf(0.01f, tr * 0.015625f - 1.0f, alpha);
    const float a2 = alpha * 0.03125f;  // 2*alpha/64
    float til[4][2];
#pragma unroll
    for (int i = 0; i < 4; ++i) {
      u32 w = *(const u32*)(PD + prow[i]);
      float pt[2] = {rlo(w), rhi(w)};
#pragma unroll
      for (int j = 0; j < 2; ++j) {
        float g = fmaf(a2 * x[i][j], pt[j], -sc[i][j]);
        til[i][j] = fmaf(-0.01f, g, x[i][j]);
      }
    }
    prox(til);
  };
  auto front = [&]() {
    mm<true, true, true>(PA, PB, PD, PE, o, red);  // f1: m30 (+free trace)
    mm<true, false>(PD, PE, PF, PF, o);            // f2: m60 -> R only
    mm_core<false, true>(PF, cC, PD, PD, o);       // f3: m63 -> T only (PD)
  };

  // ---- iteration 0: alpha == 0 -> grad = -scores ----
  {
    float til[4][2];
#pragma unroll
    for (int i = 0; i < 4; ++i)
#pragma unroll
      for (int j = 0; j < 2; ++j) til[i][j] = fmaf(0.01f, sc[i][j], x[i][j]);
    prox(til);
    stage();
    chain5();
  }
  // ---- iterations 1..48 ----
  for (int it = 0; it < 48; ++it) {
    front();
    gradprox();
    stage();
    chain5();
  }
  // ---- iteration 49: no trailing stage/chain ----
  front();
  gradprox();

  float* dst = out + (size_t)blockIdx.x * 4096;
#pragma unroll
  for (int i = 0; i < 4; ++i) {
    float2 v;
    v.x = (x[i][0] > 0.5f) ? x[i][0] : 0.0f;
    v.y = (x[i][1] > 0.5f) ? x[i][1] : 0.0f;
    *(float2*)(dst + (r0 + i) * 64 + c0) = v;
  }
}

extern "C" void kernel_launch(void* const* d_in, const int* in_sizes, int n_in,
                              void* d_out, int out_size, void* d_ws,
                              size_t ws_size, hipStream_t stream) {
  const float* adj = (const float*)d_in[0];
  float* out = (float*)d_out;
  const int nbatch = in_sizes[0] / 4096;  // 512
  dag_iter_kernel<<<nbatch, 512, 0, stream>>>(adj, out);
}